// Round 17
// baseline (44.122 us; speedup 1.0000x reference)
//
#include <hip/hip_runtime.h>

#define NS    88     // species
#define CCH   128    // channels
#define BCAP  16384  // per-species bucket capacity
#define STR   16     // stripe blocks per species (16 atoms each; grid-stride beyond)

typedef float f32x4 __attribute__((ext_vector_type(4)));
typedef unsigned short u16x4 __attribute__((ext_vector_type(4)));

__device__ inline unsigned short f2bf(float f) {   // RNE f32 -> bf16
    unsigned u = __float_as_uint(f);
    return (unsigned short)((u + 0x7FFFu + ((u >> 16) & 1u)) >> 16);
}
__device__ inline float bf2f(unsigned short h) {
    return __uint_as_float(((unsigned)h) << 16);
}

__device__ const int TRI[20][3] = {
    {0,0,0},{0,0,1},{0,0,2},{0,0,3},{0,1,1},{0,1,2},{0,1,3},{0,2,2},{0,2,3},{0,3,3},
    {1,1,1},{1,1,2},{1,1,3},{1,2,2},{1,2,3},{1,3,3},
    {2,2,2},{2,2,3},{2,3,3},
    {3,3,3}};
__device__ const int PAIR[10][2] = {
    {0,0},{0,1},{0,2},{0,3},{1,1},{1,2},{1,3},{2,2},{2,3},{3,3}};

// ---------------- fused setup: blocks 0..87 sort, 88..98 coef table ----------------
// T (bf16): [s][m(34)][c(128)][4] ushorts; m: 0..19 cubic (TRI), 20..29 pairs,
// 30..33 linear; comp[0]=0e, [1..3]=1o. Sort verified R12..R16.

__global__ __launch_bounds__(1024) void k_setup(
    const int* __restrict__ species, int N,
    const float* __restrict__ u1_0e, const float* __restrict__ w1_0e,
    const float* __restrict__ u1_1o, const float* __restrict__ w1_1o,
    const float* __restrict__ u2_0e, const float* __restrict__ w2_0e,
    const float* __restrict__ u2_1o, const float* __restrict__ w2_1o,
    const float* __restrict__ u3_0e, const float* __restrict__ w3_0e,
    const float* __restrict__ u3_1o, const float* __restrict__ w3_1o,
    unsigned short* __restrict__ T, int* __restrict__ counts, int* __restrict__ list) {

    __shared__ int wh[16];
    __shared__ float S3e[20][4];
    __shared__ float S3o[20][6][3];
    __shared__ float S2e[10][2];
    __shared__ float S2o[10][2][3];
    __shared__ float S1e[4];
    __shared__ float S1o[4][3];

    int tid = threadIdx.x;

    if (blockIdx.x < NS) {
        int s = blockIdx.x;
        int lane = tid & 63, w = tid >> 6;
        int* bucket = list + s * BCAP;
        int pos = 0;
        for (int base = 0; base < N; base += 1024) {
            int n = base + tid;
            bool m = (n < N) && (species[n] == s);
            unsigned long long b = __ballot(m);
            int rank = __popcll(b & ((1ull << lane) - 1));
            if (lane == 0) wh[w] = __popcll(b);
            __syncthreads();
            int wbase = 0, tot = 0;
#pragma unroll
            for (int i = 0; i < 16; ++i) { int v = wh[i]; if (i < w) wbase += v; tot += v; }
            if (m) bucket[pos + wbase + rank] = n;
            pos += tot;
            __syncthreads();
        }
        if (tid == 0) counts[s] = pos;
        return;
    }

    // ---- stage A: symmetrized bases into LDS (536 jobs) ----
    for (int j = tid; j < 536; j += 1024) {
        if (j < 80) {
            int m = j >> 2, k = j & 3;
            int a = TRI[m][0], b = TRI[m][1], d = TRI[m][2];
            int P[6][3] = {{a,b,d},{a,d,b},{b,a,d},{b,d,a},{d,a,b},{d,b,a}};
            float acc = 0.f;
#pragma unroll
            for (int p = 0; p < 6; ++p)
                acc += u3_0e[((P[p][0] * 4 + P[p][1]) * 4 + P[p][2]) * 4 + k];
            float inv = (a == d) ? (1.f / 6.f) : ((a == b || b == d) ? 0.5f : 1.f);
            S3e[m][k] = acc * inv;
        } else if (j < 440) {
            int r = j - 80;
            int m = r / 18, jj = r % 18, k = jj / 3, i = jj % 3;
            int a = TRI[m][0], b = TRI[m][1], d = TRI[m][2];
            int P[6][3] = {{a,b,d},{a,d,b},{b,a,d},{b,d,a},{d,a,b},{d,b,a}};
            float acc = 0.f;
#pragma unroll
            for (int p = 0; p < 6; ++p)
                acc += u3_1o[(((P[p][0] * 4 + P[p][1]) * 4 + P[p][2]) * 6 + k) * 3 + i];
            float inv = (a == d) ? (1.f / 6.f) : ((a == b || b == d) ? 0.5f : 1.f);
            S3o[m][k][i] = acc * inv;
        } else if (j < 460) {
            int r = j - 440;
            int m = r >> 1, k = r & 1;
            int a = PAIR[m][0], b = PAIR[m][1];
            float acc = u2_0e[(a * 4 + b) * 2 + k];
            if (a != b) acc += u2_0e[(b * 4 + a) * 2 + k];
            S2e[m][k] = acc;
        } else if (j < 520) {
            int r = j - 460;
            int m = r / 6, jj = r % 6, k = jj / 3, i = jj % 3;
            int a = PAIR[m][0], b = PAIR[m][1];
            float acc = u2_1o[((a * 4 + b) * 2 + k) * 3 + i];
            if (a != b) acc += u2_1o[((b * 4 + a) * 2 + k) * 3 + i];
            S2o[m][k][i] = acc;
        } else if (j < 524) {
            int d = j - 520;
            S1e[d] = u1_0e[d];
        } else {
            int r = j - 524;
            S1o[r / 3][r % 3] = u1_1o[r];
        }
    }
    __syncthreads();

    // ---- stage B: per (s,c) contraction -> bf16 T rows ----
    int tg = (blockIdx.x - NS) * 1024 + tid;             // 11*1024 = 88*128
    int s = tg >> 7, c = tg & 127;

    float wk3e[4], wk3o[6], wk2e[2], wk2o[2];
#pragma unroll
    for (int k = 0; k < 4; ++k) wk3e[k] = w3_0e[(s * 4 + k) * CCH + c];
#pragma unroll
    for (int k = 0; k < 6; ++k) wk3o[k] = w3_1o[(s * 6 + k) * CCH + c];
#pragma unroll
    for (int k = 0; k < 2; ++k) wk2e[k] = w2_0e[(s * 2 + k) * CCH + c];
#pragma unroll
    for (int k = 0; k < 2; ++k) wk2o[k] = w2_1o[(s * 2 + k) * CCH + c];
    float wk1e = w1_0e[s * CCH + c];
    float wk1o = w1_1o[s * CCH + c];

    u16x4* Trow = reinterpret_cast<u16x4*>(T) + (size_t)s * 34 * CCH + c;
#pragma unroll
    for (int m = 0; m < 20; ++m) {
        float e = 0.f;
#pragma unroll
        for (int k = 0; k < 4; ++k) e = fmaf(S3e[m][k], wk3e[k], e);
        float o[3];
#pragma unroll
        for (int i = 0; i < 3; ++i) {
            float v = 0.f;
#pragma unroll
            for (int k = 0; k < 6; ++k) v = fmaf(S3o[m][k][i], wk3o[k], v);
            o[i] = v;
        }
        u16x4 r; r.x = f2bf(e); r.y = f2bf(o[0]); r.z = f2bf(o[1]); r.w = f2bf(o[2]);
        Trow[m * CCH] = r;
    }
#pragma unroll
    for (int m = 0; m < 10; ++m) {
        float e = fmaf(S2e[m][0], wk2e[0], S2e[m][1] * wk2e[1]);
        float o[3];
#pragma unroll
        for (int i = 0; i < 3; ++i)
            o[i] = fmaf(S2o[m][0][i], wk2o[0], S2o[m][1][i] * wk2o[1]);
        u16x4 r; r.x = f2bf(e); r.y = f2bf(o[0]); r.z = f2bf(o[1]); r.w = f2bf(o[2]);
        Trow[(20 + m) * CCH] = r;
    }
#pragma unroll
    for (int d = 0; d < 4; ++d) {
        u16x4 r;
        r.x = f2bf(S1e[d] * wk1e);
        r.y = f2bf(S1o[d][0] * wk1o);
        r.z = f2bf(S1o[d][1] * wk1o);
        r.w = f2bf(S1o[d][2] * wk1o);
        Trow[(30 + d) * CCH] = r;
    }
}

// ---------------- main kernel: bf16 LDS coefs (17.4 KB), barrier-free tile loop ----------------
// Grid (NS, STR, 2): species, 16-atom stripe, channel half g. Block 256 = 4 waves;
// lane = c64, wave grp owns 4 atoms. Single barrier (after staging); per-thread
// bucket-index reads (L2-hot) replace the bidx LDS + barriers. Small state
// (~55 live floats) + (256,1) natural allocation: aiming for the <=64-VGPR /
// 8-waves-per-SIMD tier; LDS no longer binding (17.4 KB -> 9 blocks/CU).

__global__ __launch_bounds__(256) void k_main(
    const float* __restrict__ x, const unsigned short* __restrict__ T,
    const int* __restrict__ list, const int* __restrict__ counts,
    float* __restrict__ out) {
    int s = blockIdx.x;
    int cnt = counts[s];
    int t00 = (int)blockIdx.y * 16;
    if (t00 >= cnt) return;                     // block-uniform
    int g = blockIdx.z;
    int tid = threadIdx.x;
    int c64 = tid & 63, grp = tid >> 6;
    int cg = g * 64 + c64;
    const int* bucket = list + s * BCAP;

    __shared__ u16x4 lcf[34 * 64];              // 17,408 B

    const u16x4* gsrc = reinterpret_cast<const u16x4*>(T) + (size_t)s * 34 * CCH + g * 64;
    for (int i = tid; i < 34 * 64; i += 256)
        lcf[i] = gsrc[(size_t)(i >> 6) * CCH + (i & 63)];
    __syncthreads();

    constexpr int A3[20] = {0,0,0,0,0,0,0,0,0,0,1,1,1,1,1,1,2,2,2,3};
    constexpr int B3[20] = {0,0,0,0,1,1,1,2,2,3,1,1,1,2,2,3,2,2,3,3};
    constexpr int D3[20] = {0,1,2,3,1,2,3,2,3,3,1,2,3,2,3,3,2,3,3,3};
    constexpr int A2[10] = {0,0,0,0,1,1,1,2,2,3};
    constexpr int B2[10] = {0,1,2,3,1,2,3,2,3,3};

    for (int t0 = t00; t0 < cnt; t0 += STR * 16) {
        int nvalid = cnt - t0;

        int nn[4];
        f32x4 xr[4];
#pragma unroll
        for (int j = 0; j < 4; ++j) {
            int p = t0 + grp * 4 + j;
            nn[j] = bucket[p < cnt ? p : cnt - 1];
            xr[j] = *reinterpret_cast<const f32x4*>(x + (size_t)nn[j] * 512 + cg * 4);
        }

        float acc[4][4];
#pragma unroll
        for (int j = 0; j < 4; ++j)
#pragma unroll
            for (int k = 0; k < 4; ++k) acc[j][k] = 0.f;

#pragma unroll
        for (int m = 0; m < 34; ++m) {
            u16x4 cb = lcf[m * 64 + c64];
            float c0 = bf2f(cb.x), c1 = bf2f(cb.y), c2 = bf2f(cb.z), c3 = bf2f(cb.w);
#pragma unroll
            for (int j = 0; j < 4; ++j) {
                float mono;
                if (m < 20)      mono = xr[j][A3[m]] * xr[j][B3[m]] * xr[j][D3[m]];
                else if (m < 30) mono = xr[j][A2[m - 20]] * xr[j][B2[m - 20]];
                else             mono = xr[j][m - 30];
                acc[j][0] = fmaf(c0, mono, acc[j][0]);
                acc[j][1] = fmaf(c1, mono, acc[j][1]);
                acc[j][2] = fmaf(c2, mono, acc[j][2]);
                acc[j][3] = fmaf(c3, mono, acc[j][3]);
            }
        }

#pragma unroll
        for (int j = 0; j < 4; ++j) {
            if (grp * 4 + j < nvalid) {
                float* orow = out + (size_t)nn[j] * 512;
                orow[cg] = acc[j][0];
                orow[CCH + 3 * cg + 0] = acc[j][1];
                orow[CCH + 3 * cg + 1] = acc[j][2];
                orow[CCH + 3 * cg + 2] = acc[j][3];
            }
        }
    }
}

// ---------------- launch ----------------

extern "C" void kernel_launch(void* const* d_in, const int* in_sizes, int n_in,
                              void* d_out, int out_size, void* d_ws, size_t ws_size,
                              hipStream_t stream) {
    const float* x     = (const float*)d_in[0];
    const float* u1_0e = (const float*)d_in[1];
    const float* w1_0e = (const float*)d_in[2];
    const float* u1_1o = (const float*)d_in[3];
    const float* w1_1o = (const float*)d_in[4];
    const float* u2_0e = (const float*)d_in[5];
    const float* w2_0e = (const float*)d_in[6];
    const float* u2_1o = (const float*)d_in[7];
    const float* w2_1o = (const float*)d_in[8];
    const float* u3_0e = (const float*)d_in[9];
    const float* w3_0e = (const float*)d_in[10];
    const float* u3_1o = (const float*)d_in[11];
    const float* w3_1o = (const float*)d_in[12];
    const int*   spec  = (const int*)d_in[13];
    int N = in_sizes[13];
    float* out = (float*)d_out;

    char* ws = (char*)d_ws;
    unsigned short* T = (unsigned short*)ws;                 // NS*34*CCH*4 ushorts (3.06 MB)
    size_t tbytes = (size_t)NS * 34 * CCH * 4 * sizeof(unsigned short);
    int* list   = (int*)(ws + tbytes);                       // NS*BCAP ints
    int* counts = list + (size_t)NS * BCAP;                  // NS ints

    k_setup<<<NS + 11, 1024, 0, stream>>>(
        spec, N,
        u1_0e, w1_0e, u1_1o, w1_1o,
        u2_0e, w2_0e, u2_1o, w2_1o,
        u3_0e, w3_0e, u3_1o, w3_1o,
        T, counts, list);
    k_main<<<dim3(NS, STR, 2), 256, 0, stream>>>(x, T, list, counts, out);
}

// Round 18
// 36.782 us; speedup vs baseline: 1.1996x; 1.1996x over previous
//
#include <hip/hip_runtime.h>

#define NS    88     // species
#define CCH   128    // channels
#define BCAP  16384  // per-species bucket capacity
#define STR   16     // stripe blocks per species (16 atoms each; grid-stride beyond)

typedef float f32x4 __attribute__((ext_vector_type(4)));
typedef unsigned short u16x4 __attribute__((ext_vector_type(4)));

__device__ inline unsigned short f2bf(float f) {   // RNE f32 -> bf16
    unsigned u = __float_as_uint(f);
    return (unsigned short)((u + 0x7FFFu + ((u >> 16) & 1u)) >> 16);
}
__device__ inline float bf2f(unsigned short h) {
    return __uint_as_float(((unsigned)h) << 16);
}

__device__ const int TRI[20][3] = {
    {0,0,0},{0,0,1},{0,0,2},{0,0,3},{0,1,1},{0,1,2},{0,1,3},{0,2,2},{0,2,3},{0,3,3},
    {1,1,1},{1,1,2},{1,1,3},{1,2,2},{1,2,3},{1,3,3},
    {2,2,2},{2,2,3},{2,3,3},
    {3,3,3}};
__device__ const int PAIR[10][2] = {
    {0,0},{0,1},{0,2},{0,3},{1,1},{1,2},{1,3},{2,2},{2,3},{3,3}};

// ---------------- fused setup: blocks 0..87 sort, 88..98 coef table (R17-verified) ----------------
// T (bf16): [s][m(34)][c(128)][4] ushorts; m: 0..19 cubic (TRI), 20..29 pairs,
// 30..33 linear; comp[0]=0e, [1..3]=1o.

__global__ __launch_bounds__(1024) void k_setup(
    const int* __restrict__ species, int N,
    const float* __restrict__ u1_0e, const float* __restrict__ w1_0e,
    const float* __restrict__ u1_1o, const float* __restrict__ w1_1o,
    const float* __restrict__ u2_0e, const float* __restrict__ w2_0e,
    const float* __restrict__ u2_1o, const float* __restrict__ w2_1o,
    const float* __restrict__ u3_0e, const float* __restrict__ w3_0e,
    const float* __restrict__ u3_1o, const float* __restrict__ w3_1o,
    unsigned short* __restrict__ T, int* __restrict__ counts, int* __restrict__ list) {

    __shared__ int wh[16];
    __shared__ float S3e[20][4];
    __shared__ float S3o[20][6][3];
    __shared__ float S2e[10][2];
    __shared__ float S2o[10][2][3];
    __shared__ float S1e[4];
    __shared__ float S1o[4][3];

    int tid = threadIdx.x;

    if (blockIdx.x < NS) {
        int s = blockIdx.x;
        int lane = tid & 63, w = tid >> 6;
        int* bucket = list + s * BCAP;
        int pos = 0;
        for (int base = 0; base < N; base += 1024) {
            int n = base + tid;
            bool m = (n < N) && (species[n] == s);
            unsigned long long b = __ballot(m);
            int rank = __popcll(b & ((1ull << lane) - 1));
            if (lane == 0) wh[w] = __popcll(b);
            __syncthreads();
            int wbase = 0, tot = 0;
#pragma unroll
            for (int i = 0; i < 16; ++i) { int v = wh[i]; if (i < w) wbase += v; tot += v; }
            if (m) bucket[pos + wbase + rank] = n;
            pos += tot;
            __syncthreads();
        }
        if (tid == 0) counts[s] = pos;
        return;
    }

    // ---- stage A: symmetrized bases into LDS (536 jobs) ----
    for (int j = tid; j < 536; j += 1024) {
        if (j < 80) {
            int m = j >> 2, k = j & 3;
            int a = TRI[m][0], b = TRI[m][1], d = TRI[m][2];
            int P[6][3] = {{a,b,d},{a,d,b},{b,a,d},{b,d,a},{d,a,b},{d,b,a}};
            float acc = 0.f;
#pragma unroll
            for (int p = 0; p < 6; ++p)
                acc += u3_0e[((P[p][0] * 4 + P[p][1]) * 4 + P[p][2]) * 4 + k];
            float inv = (a == d) ? (1.f / 6.f) : ((a == b || b == d) ? 0.5f : 1.f);
            S3e[m][k] = acc * inv;
        } else if (j < 440) {
            int r = j - 80;
            int m = r / 18, jj = r % 18, k = jj / 3, i = jj % 3;
            int a = TRI[m][0], b = TRI[m][1], d = TRI[m][2];
            int P[6][3] = {{a,b,d},{a,d,b},{b,a,d},{b,d,a},{d,a,b},{d,b,a}};
            float acc = 0.f;
#pragma unroll
            for (int p = 0; p < 6; ++p)
                acc += u3_1o[(((P[p][0] * 4 + P[p][1]) * 4 + P[p][2]) * 6 + k) * 3 + i];
            float inv = (a == d) ? (1.f / 6.f) : ((a == b || b == d) ? 0.5f : 1.f);
            S3o[m][k][i] = acc * inv;
        } else if (j < 460) {
            int r = j - 440;
            int m = r >> 1, k = r & 1;
            int a = PAIR[m][0], b = PAIR[m][1];
            float acc = u2_0e[(a * 4 + b) * 2 + k];
            if (a != b) acc += u2_0e[(b * 4 + a) * 2 + k];
            S2e[m][k] = acc;
        } else if (j < 520) {
            int r = j - 460;
            int m = r / 6, jj = r % 6, k = jj / 3, i = jj % 3;
            int a = PAIR[m][0], b = PAIR[m][1];
            float acc = u2_1o[((a * 4 + b) * 2 + k) * 3 + i];
            if (a != b) acc += u2_1o[((b * 4 + a) * 2 + k) * 3 + i];
            S2o[m][k][i] = acc;
        } else if (j < 524) {
            int d = j - 520;
            S1e[d] = u1_0e[d];
        } else {
            int r = j - 524;
            S1o[r / 3][r % 3] = u1_1o[r];
        }
    }
    __syncthreads();

    // ---- stage B: per (s,c) contraction -> bf16 T rows ----
    int tg = (blockIdx.x - NS) * 1024 + tid;             // 11*1024 = 88*128
    int s = tg >> 7, c = tg & 127;

    float wk3e[4], wk3o[6], wk2e[2], wk2o[2];
#pragma unroll
    for (int k = 0; k < 4; ++k) wk3e[k] = w3_0e[(s * 4 + k) * CCH + c];
#pragma unroll
    for (int k = 0; k < 6; ++k) wk3o[k] = w3_1o[(s * 6 + k) * CCH + c];
#pragma unroll
    for (int k = 0; k < 2; ++k) wk2e[k] = w2_0e[(s * 2 + k) * CCH + c];
#pragma unroll
    for (int k = 0; k < 2; ++k) wk2o[k] = w2_1o[(s * 2 + k) * CCH + c];
    float wk1e = w1_0e[s * CCH + c];
    float wk1o = w1_1o[s * CCH + c];

    u16x4* Trow = reinterpret_cast<u16x4*>(T) + (size_t)s * 34 * CCH + c;
#pragma unroll
    for (int m = 0; m < 20; ++m) {
        float e = 0.f;
#pragma unroll
        for (int k = 0; k < 4; ++k) e = fmaf(S3e[m][k], wk3e[k], e);
        float o[3];
#pragma unroll
        for (int i = 0; i < 3; ++i) {
            float v = 0.f;
#pragma unroll
            for (int k = 0; k < 6; ++k) v = fmaf(S3o[m][k][i], wk3o[k], v);
            o[i] = v;
        }
        u16x4 r; r.x = f2bf(e); r.y = f2bf(o[0]); r.z = f2bf(o[1]); r.w = f2bf(o[2]);
        Trow[m * CCH] = r;
    }
#pragma unroll
    for (int m = 0; m < 10; ++m) {
        float e = fmaf(S2e[m][0], wk2e[0], S2e[m][1] * wk2e[1]);
        float o[3];
#pragma unroll
        for (int i = 0; i < 3; ++i)
            o[i] = fmaf(S2o[m][0][i], wk2o[0], S2o[m][1][i] * wk2o[1]);
        u16x4 r; r.x = f2bf(e); r.y = f2bf(o[0]); r.z = f2bf(o[1]); r.w = f2bf(o[2]);
        Trow[(20 + m) * CCH] = r;
    }
#pragma unroll
    for (int d = 0; d < 4; ++d) {
        u16x4 r;
        r.x = f2bf(S1e[d] * wk1e);
        r.y = f2bf(S1o[d][0] * wk1o);
        r.z = f2bf(S1o[d][1] * wk1o);
        r.w = f2bf(S1o[d][2] * wk1o);
        Trow[(30 + d) * CCH] = r;
    }
}

// ---------------- main kernel: R17 compute + LDS-transposed COALESCED stores ----------------
// Grid (NS, STR, 2): species, 16-atom stripe, channel half g. Block 256 = 4 waves.
// Compute phase identical to R17 (bf16 LDS coefs). NEW: acc goes to lstage[16][256]
// via LDS (1o is a stride-3 LDS write = 2 lanes/bank = free), then a cooperative
// store phase writes each atom's half-row as TWO contiguous runs: o0 = 256 B at
// n*512+g*64, 1o = 768 B at n*512+128+g*192 — replacing the 12-B-stride global
// scatter (12 line-touches/wave-store) that every prior k_main shared.

__global__ __launch_bounds__(256) void k_main(
    const float* __restrict__ x, const unsigned short* __restrict__ T,
    const int* __restrict__ list, const int* __restrict__ counts,
    float* __restrict__ out) {
    int s = blockIdx.x;
    int cnt = counts[s];
    int t00 = (int)blockIdx.y * 16;
    if (t00 >= cnt) return;                     // block-uniform
    int g = blockIdx.z;
    int tid = threadIdx.x;
    int c64 = tid & 63, grp = tid >> 6;
    int cg = g * 64 + c64;
    const int* bucket = list + s * BCAP;

    __shared__ u16x4 lcf[34 * 64];              // 17,408 B
    __shared__ float lstage[16][256];           // 16,384 B

    const u16x4* gsrc = reinterpret_cast<const u16x4*>(T) + (size_t)s * 34 * CCH + g * 64;
    for (int i = tid; i < 34 * 64; i += 256)
        lcf[i] = gsrc[(size_t)(i >> 6) * CCH + (i & 63)];
    __syncthreads();

    constexpr int A3[20] = {0,0,0,0,0,0,0,0,0,0,1,1,1,1,1,1,2,2,2,3};
    constexpr int B3[20] = {0,0,0,0,1,1,1,2,2,3,1,1,1,2,2,3,2,2,3,3};
    constexpr int D3[20] = {0,1,2,3,1,2,3,2,3,3,1,2,3,2,3,3,2,3,3,3};
    constexpr int A2[10] = {0,0,0,0,1,1,1,2,2,3};
    constexpr int B2[10] = {0,1,2,3,1,2,3,2,3,3};

    for (int t0 = t00; t0 < cnt; t0 += STR * 16) {
        int nvalid = cnt - t0;

        // ---- compute (identical to R17) ----
        int nn[4];
        f32x4 xr[4];
#pragma unroll
        for (int j = 0; j < 4; ++j) {
            int p = t0 + grp * 4 + j;
            nn[j] = bucket[p < cnt ? p : cnt - 1];
            xr[j] = *reinterpret_cast<const f32x4*>(x + (size_t)nn[j] * 512 + cg * 4);
        }

        float acc[4][4];
#pragma unroll
        for (int j = 0; j < 4; ++j)
#pragma unroll
            for (int k = 0; k < 4; ++k) acc[j][k] = 0.f;

#pragma unroll
        for (int m = 0; m < 34; ++m) {
            u16x4 cb = lcf[m * 64 + c64];
            float c0 = bf2f(cb.x), c1 = bf2f(cb.y), c2 = bf2f(cb.z), c3 = bf2f(cb.w);
#pragma unroll
            for (int j = 0; j < 4; ++j) {
                float mono;
                if (m < 20)      mono = xr[j][A3[m]] * xr[j][B3[m]] * xr[j][D3[m]];
                else if (m < 30) mono = xr[j][A2[m - 20]] * xr[j][B2[m - 20]];
                else             mono = xr[j][m - 30];
                acc[j][0] = fmaf(c0, mono, acc[j][0]);
                acc[j][1] = fmaf(c1, mono, acc[j][1]);
                acc[j][2] = fmaf(c2, mono, acc[j][2]);
                acc[j][3] = fmaf(c3, mono, acc[j][3]);
            }
        }

        // ---- transpose through LDS ----
#pragma unroll
        for (int j = 0; j < 4; ++j) {
            int a = grp * 4 + j;
            lstage[a][c64] = acc[j][0];
            lstage[a][64 + 3 * c64 + 0] = acc[j][1];
            lstage[a][64 + 3 * c64 + 1] = acc[j][2];
            lstage[a][64 + 3 * c64 + 2] = acc[j][3];
        }
        __syncthreads();

        // ---- cooperative coalesced store: 1024 f32x4 chunks, 4 per thread ----
#pragma unroll
        for (int q = 0; q < 4; ++q) {
            int chunk = tid + q * 256;
            int a = chunk >> 6, k = chunk & 63;
            if (a < nvalid) {
                int n = bucket[t0 + a];
                f32x4 v = *reinterpret_cast<const f32x4*>(&lstage[a][k * 4]);
                float* dst = (k < 16)
                    ? out + (size_t)n * 512 + g * 64 + k * 4
                    : out + (size_t)n * 512 + 128 + g * 192 + (k * 4 - 64);
                *reinterpret_cast<f32x4*>(dst) = v;
            }
        }
        __syncthreads();
    }
}

// ---------------- launch ----------------

extern "C" void kernel_launch(void* const* d_in, const int* in_sizes, int n_in,
                              void* d_out, int out_size, void* d_ws, size_t ws_size,
                              hipStream_t stream) {
    const float* x     = (const float*)d_in[0];
    const float* u1_0e = (const float*)d_in[1];
    const float* w1_0e = (const float*)d_in[2];
    const float* u1_1o = (const float*)d_in[3];
    const float* w1_1o = (const float*)d_in[4];
    const float* u2_0e = (const float*)d_in[5];
    const float* w2_0e = (const float*)d_in[6];
    const float* u2_1o = (const float*)d_in[7];
    const float* w2_1o = (const float*)d_in[8];
    const float* u3_0e = (const float*)d_in[9];
    const float* w3_0e = (const float*)d_in[10];
    const float* u3_1o = (const float*)d_in[11];
    const float* w3_1o = (const float*)d_in[12];
    const int*   spec  = (const int*)d_in[13];
    int N = in_sizes[13];
    float* out = (float*)d_out;

    char* ws = (char*)d_ws;
    unsigned short* T = (unsigned short*)ws;                 // NS*34*CCH*4 ushorts (3.06 MB)
    size_t tbytes = (size_t)NS * 34 * CCH * 4 * sizeof(unsigned short);
    int* list   = (int*)(ws + tbytes);                       // NS*BCAP ints
    int* counts = list + (size_t)NS * BCAP;                  // NS ints

    k_setup<<<NS + 11, 1024, 0, stream>>>(
        spec, N,
        u1_0e, w1_0e, u1_1o, w1_1o,
        u2_0e, w2_0e, u2_1o, w2_1o,
        u3_0e, w3_0e, u3_1o, w3_1o,
        T, counts, list);
    k_main<<<dim3(NS, STR, 2), 256, 0, stream>>>(x, T, list, counts, out);
}

// Round 19
// 36.041 us; speedup vs baseline: 1.2242x; 1.0206x over previous
//
#include <hip/hip_runtime.h>

#define NS    88     // species
#define CCH   128    // channels
#define BCAP  16384  // per-species bucket capacity
#define STR   16     // stripe blocks per species (16 atoms each; grid-stride beyond)

typedef float f32x4 __attribute__((ext_vector_type(4)));
typedef unsigned short u16x4 __attribute__((ext_vector_type(4)));

__device__ inline unsigned short f2bf(float f) {   // RNE f32 -> bf16
    unsigned u = __float_as_uint(f);
    return (unsigned short)((u + 0x7FFFu + ((u >> 16) & 1u)) >> 16);
}
__device__ inline float bf2f(unsigned short h) {
    return __uint_as_float(((unsigned)h) << 16);
}

__device__ const int TRI[20][3] = {
    {0,0,0},{0,0,1},{0,0,2},{0,0,3},{0,1,1},{0,1,2},{0,1,3},{0,2,2},{0,2,3},{0,3,3},
    {1,1,1},{1,1,2},{1,1,3},{1,2,2},{1,2,3},{1,3,3},
    {2,2,2},{2,2,3},{2,3,3},
    {3,3,3}};
__device__ const int PAIR[10][2] = {
    {0,0},{0,1},{0,2},{0,3},{1,1},{1,2},{1,3},{2,2},{2,3},{3,3}};

// ---------------- fused setup: blocks 0..87 sort, 88..98 coef table ----------------
// Sort: wave-chunked (R2-verified scheme) — 16 waves each own a contiguous N/16
// slice; pass1 ballot-count (no barriers), ONE barrier, pass2 rank-scatter (no
// barriers). Globally ascending, deterministic, atomic-free.
// Table (R17/R18-verified): T (bf16) [s][m(34)][c(128)][4]; m: 0..19 cubic (TRI),
// 20..29 pairs, 30..33 linear; comp[0]=0e, [1..3]=1o.

__global__ __launch_bounds__(1024) void k_setup(
    const int* __restrict__ species, int N,
    const float* __restrict__ u1_0e, const float* __restrict__ w1_0e,
    const float* __restrict__ u1_1o, const float* __restrict__ w1_1o,
    const float* __restrict__ u2_0e, const float* __restrict__ w2_0e,
    const float* __restrict__ u2_1o, const float* __restrict__ w2_1o,
    const float* __restrict__ u3_0e, const float* __restrict__ w3_0e,
    const float* __restrict__ u3_1o, const float* __restrict__ w3_1o,
    unsigned short* __restrict__ T, int* __restrict__ counts, int* __restrict__ list) {

    __shared__ int wh[16];
    __shared__ float S3e[20][4];
    __shared__ float S3o[20][6][3];
    __shared__ float S2e[10][2];
    __shared__ float S2o[10][2][3];
    __shared__ float S1e[4];
    __shared__ float S1o[4][3];

    int tid = threadIdx.x;

    if (blockIdx.x < NS) {
        int s = blockIdx.x;
        int lane = tid & 63, w = tid >> 6;
        int* bucket = list + s * BCAP;
        int chunk = ((N + 1023) >> 10) << 6;     // per-wave slice, multiple of 64
        int cbeg = w * chunk, cend = min(N, cbeg + chunk);
        // pass 1: per-wave match count (loads pipeline, no barriers)
        int cnt = 0;
        for (int base = cbeg; base < cend; base += 64) {
            int n = base + lane;
            bool m = (n < cend) && (species[n] == s);
            cnt += __popcll(__ballot(m));
        }
        if (lane == 0) wh[w] = cnt;
        __syncthreads();
        int pos = 0, tot = 0;
#pragma unroll
        for (int i = 0; i < 16; ++i) { int v = wh[i]; if (i < w) pos += v; tot += v; }
        // pass 2: wave-local ordered scatter (no barriers)
        for (int base = cbeg; base < cend; base += 64) {
            int n = base + lane;
            bool m = (n < cend) && (species[n] == s);
            unsigned long long b = __ballot(m);
            int rank = __popcll(b & ((1ull << lane) - 1));
            if (m) bucket[pos + rank] = n;
            pos += __popcll(b);
        }
        if (tid == 0) counts[s] = tot;
        return;
    }

    // ---- stage A: symmetrized bases into LDS (536 jobs) ----
    for (int j = tid; j < 536; j += 1024) {
        if (j < 80) {
            int m = j >> 2, k = j & 3;
            int a = TRI[m][0], b = TRI[m][1], d = TRI[m][2];
            int P[6][3] = {{a,b,d},{a,d,b},{b,a,d},{b,d,a},{d,a,b},{d,b,a}};
            float acc = 0.f;
#pragma unroll
            for (int p = 0; p < 6; ++p)
                acc += u3_0e[((P[p][0] * 4 + P[p][1]) * 4 + P[p][2]) * 4 + k];
            float inv = (a == d) ? (1.f / 6.f) : ((a == b || b == d) ? 0.5f : 1.f);
            S3e[m][k] = acc * inv;
        } else if (j < 440) {
            int r = j - 80;
            int m = r / 18, jj = r % 18, k = jj / 3, i = jj % 3;
            int a = TRI[m][0], b = TRI[m][1], d = TRI[m][2];
            int P[6][3] = {{a,b,d},{a,d,b},{b,a,d},{b,d,a},{d,a,b},{d,b,a}};
            float acc = 0.f;
#pragma unroll
            for (int p = 0; p < 6; ++p)
                acc += u3_1o[(((P[p][0] * 4 + P[p][1]) * 4 + P[p][2]) * 6 + k) * 3 + i];
            float inv = (a == d) ? (1.f / 6.f) : ((a == b || b == d) ? 0.5f : 1.f);
            S3o[m][k][i] = acc * inv;
        } else if (j < 460) {
            int r = j - 440;
            int m = r >> 1, k = r & 1;
            int a = PAIR[m][0], b = PAIR[m][1];
            float acc = u2_0e[(a * 4 + b) * 2 + k];
            if (a != b) acc += u2_0e[(b * 4 + a) * 2 + k];
            S2e[m][k] = acc;
        } else if (j < 520) {
            int r = j - 460;
            int m = r / 6, jj = r % 6, k = jj / 3, i = jj % 3;
            int a = PAIR[m][0], b = PAIR[m][1];
            float acc = u2_1o[((a * 4 + b) * 2 + k) * 3 + i];
            if (a != b) acc += u2_1o[((b * 4 + a) * 2 + k) * 3 + i];
            S2o[m][k][i] = acc;
        } else if (j < 524) {
            int d = j - 520;
            S1e[d] = u1_0e[d];
        } else {
            int r = j - 524;
            S1o[r / 3][r % 3] = u1_1o[r];
        }
    }
    __syncthreads();

    // ---- stage B: per (s,c) contraction -> bf16 T rows ----
    int tg = (blockIdx.x - NS) * 1024 + tid;             // 11*1024 = 88*128
    int s = tg >> 7, c = tg & 127;

    float wk3e[4], wk3o[6], wk2e[2], wk2o[2];
#pragma unroll
    for (int k = 0; k < 4; ++k) wk3e[k] = w3_0e[(s * 4 + k) * CCH + c];
#pragma unroll
    for (int k = 0; k < 6; ++k) wk3o[k] = w3_1o[(s * 6 + k) * CCH + c];
#pragma unroll
    for (int k = 0; k < 2; ++k) wk2e[k] = w2_0e[(s * 2 + k) * CCH + c];
#pragma unroll
    for (int k = 0; k < 2; ++k) wk2o[k] = w2_1o[(s * 2 + k) * CCH + c];
    float wk1e = w1_0e[s * CCH + c];
    float wk1o = w1_1o[s * CCH + c];

    u16x4* Trow = reinterpret_cast<u16x4*>(T) + (size_t)s * 34 * CCH + c;
#pragma unroll
    for (int m = 0; m < 20; ++m) {
        float e = 0.f;
#pragma unroll
        for (int k = 0; k < 4; ++k) e = fmaf(S3e[m][k], wk3e[k], e);
        float o[3];
#pragma unroll
        for (int i = 0; i < 3; ++i) {
            float v = 0.f;
#pragma unroll
            for (int k = 0; k < 6; ++k) v = fmaf(S3o[m][k][i], wk3o[k], v);
            o[i] = v;
        }
        u16x4 r; r.x = f2bf(e); r.y = f2bf(o[0]); r.z = f2bf(o[1]); r.w = f2bf(o[2]);
        Trow[m * CCH] = r;
    }
#pragma unroll
    for (int m = 0; m < 10; ++m) {
        float e = fmaf(S2e[m][0], wk2e[0], S2e[m][1] * wk2e[1]);
        float o[3];
#pragma unroll
        for (int i = 0; i < 3; ++i)
            o[i] = fmaf(S2o[m][0][i], wk2o[0], S2o[m][1][i] * wk2o[1]);
        u16x4 r; r.x = f2bf(e); r.y = f2bf(o[0]); r.z = f2bf(o[1]); r.w = f2bf(o[2]);
        Trow[(20 + m) * CCH] = r;
    }
#pragma unroll
    for (int d = 0; d < 4; ++d) {
        u16x4 r;
        r.x = f2bf(S1e[d] * wk1e);
        r.y = f2bf(S1o[d][0] * wk1o);
        r.z = f2bf(S1o[d][1] * wk1o);
        r.w = f2bf(S1o[d][2] * wk1o);
        Trow[(30 + d) * CCH] = r;
    }
}

// ---------------- main kernel: R18 compute + coalesced stores, NT streams ----------------
// Grid (NS, STR, 2): species, 16-atom stripe, channel half g. Block 256 = 4 waves.
// bf16 LDS coefs (17.4 KB) + lstage transpose (16 KB). NT x-loads / out-stores keep
// the 3 MB T table + buckets L2-resident across the per-block re-staging.

__global__ __launch_bounds__(256) void k_main(
    const float* __restrict__ x, const unsigned short* __restrict__ T,
    const int* __restrict__ list, const int* __restrict__ counts,
    float* __restrict__ out) {
    int s = blockIdx.x;
    int cnt = counts[s];
    int t00 = (int)blockIdx.y * 16;
    if (t00 >= cnt) return;                     // block-uniform
    int g = blockIdx.z;
    int tid = threadIdx.x;
    int c64 = tid & 63, grp = tid >> 6;
    int cg = g * 64 + c64;
    const int* bucket = list + s * BCAP;

    __shared__ u16x4 lcf[34 * 64];              // 17,408 B
    __shared__ float lstage[16][256];           // 16,384 B

    const u16x4* gsrc = reinterpret_cast<const u16x4*>(T) + (size_t)s * 34 * CCH + g * 64;
    for (int i = tid; i < 34 * 64; i += 256)
        lcf[i] = gsrc[(size_t)(i >> 6) * CCH + (i & 63)];
    __syncthreads();

    constexpr int A3[20] = {0,0,0,0,0,0,0,0,0,0,1,1,1,1,1,1,2,2,2,3};
    constexpr int B3[20] = {0,0,0,0,1,1,1,2,2,3,1,1,1,2,2,3,2,2,3,3};
    constexpr int D3[20] = {0,1,2,3,1,2,3,2,3,3,1,2,3,2,3,3,2,3,3,3};
    constexpr int A2[10] = {0,0,0,0,1,1,1,2,2,3};
    constexpr int B2[10] = {0,1,2,3,1,2,3,2,3,3};

    for (int t0 = t00; t0 < cnt; t0 += STR * 16) {
        int nvalid = cnt - t0;

        // ---- compute ----
        int nn[4];
        f32x4 xr[4];
#pragma unroll
        for (int j = 0; j < 4; ++j) {
            int p = t0 + grp * 4 + j;
            nn[j] = bucket[p < cnt ? p : cnt - 1];
            xr[j] = __builtin_nontemporal_load(
                reinterpret_cast<const f32x4*>(x + (size_t)nn[j] * 512 + cg * 4));
        }

        float acc[4][4];
#pragma unroll
        for (int j = 0; j < 4; ++j)
#pragma unroll
            for (int k = 0; k < 4; ++k) acc[j][k] = 0.f;

#pragma unroll
        for (int m = 0; m < 34; ++m) {
            u16x4 cb = lcf[m * 64 + c64];
            float c0 = bf2f(cb.x), c1 = bf2f(cb.y), c2 = bf2f(cb.z), c3 = bf2f(cb.w);
#pragma unroll
            for (int j = 0; j < 4; ++j) {
                float mono;
                if (m < 20)      mono = xr[j][A3[m]] * xr[j][B3[m]] * xr[j][D3[m]];
                else if (m < 30) mono = xr[j][A2[m - 20]] * xr[j][B2[m - 20]];
                else             mono = xr[j][m - 30];
                acc[j][0] = fmaf(c0, mono, acc[j][0]);
                acc[j][1] = fmaf(c1, mono, acc[j][1]);
                acc[j][2] = fmaf(c2, mono, acc[j][2]);
                acc[j][3] = fmaf(c3, mono, acc[j][3]);
            }
        }

        // ---- transpose through LDS (stride-3 write = 2 lanes/bank = free) ----
#pragma unroll
        for (int j = 0; j < 4; ++j) {
            int a = grp * 4 + j;
            lstage[a][c64] = acc[j][0];
            lstage[a][64 + 3 * c64 + 0] = acc[j][1];
            lstage[a][64 + 3 * c64 + 1] = acc[j][2];
            lstage[a][64 + 3 * c64 + 2] = acc[j][3];
        }
        __syncthreads();

        // ---- cooperative coalesced store: one atom per wave-pass, two runs ----
#pragma unroll
        for (int q = 0; q < 4; ++q) {
            int chunk = tid + q * 256;
            int a = chunk >> 6, k = chunk & 63;
            if (a < nvalid) {
                int n = bucket[t0 + a];
                f32x4 v = *reinterpret_cast<const f32x4*>(&lstage[a][k * 4]);
                float* dst = (k < 16)
                    ? out + (size_t)n * 512 + g * 64 + k * 4
                    : out + (size_t)n * 512 + 128 + g * 192 + (k * 4 - 64);
                __builtin_nontemporal_store(v, reinterpret_cast<f32x4*>(dst));
            }
        }
        __syncthreads();
    }
}

// ---------------- launch ----------------

extern "C" void kernel_launch(void* const* d_in, const int* in_sizes, int n_in,
                              void* d_out, int out_size, void* d_ws, size_t ws_size,
                              hipStream_t stream) {
    const float* x     = (const float*)d_in[0];
    const float* u1_0e = (const float*)d_in[1];
    const float* w1_0e = (const float*)d_in[2];
    const float* u1_1o = (const float*)d_in[3];
    const float* w1_1o = (const float*)d_in[4];
    const float* u2_0e = (const float*)d_in[5];
    const float* w2_0e = (const float*)d_in[6];
    const float* u2_1o = (const float*)d_in[7];
    const float* w2_1o = (const float*)d_in[8];
    const float* u3_0e = (const float*)d_in[9];
    const float* w3_0e = (const float*)d_in[10];
    const float* u3_1o = (const float*)d_in[11];
    const float* w3_1o = (const float*)d_in[12];
    const int*   spec  = (const int*)d_in[13];
    int N = in_sizes[13];
    float* out = (float*)d_out;

    char* ws = (char*)d_ws;
    unsigned short* T = (unsigned short*)ws;                 // NS*34*CCH*4 ushorts (3.06 MB)
    size_t tbytes = (size_t)NS * 34 * CCH * 4 * sizeof(unsigned short);
    int* list   = (int*)(ws + tbytes);                       // NS*BCAP ints
    int* counts = list + (size_t)NS * BCAP;                  // NS ints

    k_setup<<<NS + 11, 1024, 0, stream>>>(
        spec, N,
        u1_0e, w1_0e, u1_1o, w1_1o,
        u2_0e, w2_0e, u2_1o, w2_1o,
        u3_0e, w3_0e, u3_1o, w3_1o,
        T, counts, list);
    k_main<<<dim3(NS, STR, 2), 256, 0, stream>>>(x, T, list, counts, out);
}